// Round 6
// baseline (99.140 us; speedup 1.0000x reference)
//
#include <hip/hip_runtime.h>
#include <math.h>

#define NPOLE 32     // N2
#define SLEN 2048    // L
#define NHALF 1024   // L/2

// R6 = R5 kernel with a runtime-repeat loop (reps=2) around the compute body.
// Purpose: slope calibration. dur(reps=2) - dur(reps=1-equivalent R5 bench)
// equals the true kernel time, decomposing harness overhead vs kernel inside
// the opaque timed region. Output is bit-identical to R5 (second pass
// recomputes and rewrites the same values; `reps` is a kernel arg so the
// compiler cannot fold the loop).
__global__ __launch_bounds__(512) void s4_nplr_kernel(
    const float* __restrict__ g_log_dt,
    const float* __restrict__ g_log_w_real,
    const float* __restrict__ g_w_imag,
    const float* __restrict__ g_B,
    const float* __restrict__ g_C,
    const float* __restrict__ g_P,
    float* __restrict__ g_out,
    int reps)
{
    const int h   = blockIdx.x;
    const int tid = threadIdx.x;

    __shared__ float4 sA[NPOLE];      // {ar, wim, dt*v00r, dt*v00i}  ar = -Re(w)*dt
    __shared__ float4 sB[NPOLE];      // dt*{v01r, v01i, v10r, v10i}
    __shared__ float  sC[NPOLE];      // dt*v11r
    __shared__ __align__(16) float2 bufA[NHALF];
    __shared__ __align__(16) float2 bufB[NHALF];
    __shared__ float2 stw[512];       // FFT twiddles e^{+i*pi*k/512}
    __shared__ float2 s_kf_last;      // k_f[1024]

    const float dt = expf(g_log_dt[h]);

    if (tid < NPOLE) {
        const int n   = tid;
        const int idx = h * NPOLE + n;
        const float ar  = expf(g_log_w_real[idx]) * dt;   // -Re(w)*dt > 0
        const float wim = g_w_imag[idx] * dt;
        const float Br = g_B[2*idx+0], Bi = g_B[2*idx+1];
        const float Cr = g_C[2*idx+0], Ci = g_C[2*idx+1];
        const float Pr = g_P[2*idx+0], Pi = g_P[2*idx+1];
        // v00=B*C, v01=B*conj(P), v10=P*C, v11=|P|^2 ; dt folded in
        sA[n] = make_float4(ar, wim, dt*(Br*Cr - Bi*Ci), dt*(Br*Ci + Bi*Cr));
        sB[n] = make_float4(dt*(Br*Pr + Bi*Pi), dt*(Bi*Pr - Br*Pi),
                            dt*(Pr*Cr - Pi*Ci), dt*(Pr*Ci + Pi*Cr));
        sC[n] = dt*(Pr*Pr + Pi*Pi);
    }
    // FFT twiddle table: stw[k] = e^{+i*pi*k/512} = cis(2*pi * k/1024)
    {
        const float rev = (float)tid * (1.0f / 1024.0f);
        stw[tid] = make_float2(__builtin_amdgcn_cosf(rev),
                               __builtin_amdgcn_sinf(rev));
    }
    __syncthreads();

    for (int rep = 0; rep < reps; ++rep) {
        // ---- Phase B: 2 m-nodes per thread (mA = tid, mB = tid+512) ----
        {
            const int mA = tid;
            const int mB = tid + 512;
            // t = tan(pi*m/2048) = sin(rev)/cos(rev), rev = m/4096 in [0, 0.25)
            const float revA = (float)mA * (1.0f / 4096.0f);
            const float revB = (float)mB * (1.0f / 4096.0f);
            const float tA = __builtin_amdgcn_sinf(revA) *
                             __builtin_amdgcn_rcpf(__builtin_amdgcn_cosf(revA));
            const float tB = __builtin_amdgcn_sinf(revB) *
                             __builtin_amdgcn_rcpf(__builtin_amdgcn_cosf(revB));
            const float t2A = tA + tA, t2B = tB + tB;

            float a00r=0.f,a00i=0.f,a01r=0.f,a01i=0.f,a10r=0.f,a10i=0.f,a11r=0.f,a11i=0.f;
            float b00r=0.f,b00i=0.f,b01r=0.f,b01i=0.f,b10r=0.f,b10i=0.f,b11r=0.f,b11i=0.f;

            #pragma unroll 8
            for (int n = 0; n < NPOLE; ++n) {
                const float4 a  = sA[n];
                const float4 b  = sB[n];
                const float v11 = sC[n];
                const float ar = a.x, wim = a.y;
                const float ar2 = ar * ar;
                // node A
                {
                    float aim = t2A - wim, aip = t2A + wim;
                    float inv1 = __builtin_amdgcn_rcpf(fmaf(aim, aim, ar2));
                    float inv2 = __builtin_amdgcn_rcpf(fmaf(aip, aip, ar2));
                    float d1r = ar * inv1,   e2r = ar * inv2;
                    float d1i = -aim * inv1, e2i = -aip * inv2;
                    float Sr = d1r + e2r, Dr = d1r - e2r;
                    float Si = d1i + e2i, Di = e2i - d1i;
                    a00r = fmaf(a.z, Sr, fmaf(a.w, Di, a00r));
                    a00i = fmaf(a.z, Si, fmaf(a.w, Dr, a00i));
                    a01r = fmaf(b.x, Sr, fmaf(b.y, Di, a01r));
                    a01i = fmaf(b.x, Si, fmaf(b.y, Dr, a01i));
                    a10r = fmaf(b.z, Sr, fmaf(b.w, Di, a10r));
                    a10i = fmaf(b.z, Si, fmaf(b.w, Dr, a10i));
                    a11r = fmaf(v11, Sr, a11r);
                    a11i = fmaf(v11, Si, a11i);
                }
                // node B
                {
                    float aim = t2B - wim, aip = t2B + wim;
                    float inv1 = __builtin_amdgcn_rcpf(fmaf(aim, aim, ar2));
                    float inv2 = __builtin_amdgcn_rcpf(fmaf(aip, aip, ar2));
                    float d1r = ar * inv1,   e2r = ar * inv2;
                    float d1i = -aim * inv1, e2i = -aip * inv2;
                    float Sr = d1r + e2r, Dr = d1r - e2r;
                    float Si = d1i + e2i, Di = e2i - d1i;
                    b00r = fmaf(a.z, Sr, fmaf(a.w, Di, b00r));
                    b00i = fmaf(a.z, Si, fmaf(a.w, Dr, b00i));
                    b01r = fmaf(b.x, Sr, fmaf(b.y, Di, b01r));
                    b01i = fmaf(b.x, Si, fmaf(b.y, Dr, b01i));
                    b10r = fmaf(b.z, Sr, fmaf(b.w, Di, b10r));
                    b10i = fmaf(b.z, Si, fmaf(b.w, Dr, b10i));
                    b11r = fmaf(v11, Sr, b11r);
                    b11i = fmaf(v11, Si, b11i);
                }
            }

            // Woodbury + spectral factor (1 + i*t), node A
            {
                float wdr = 1.0f + a11r, wdi = a11i;
                float winv = __builtin_amdgcn_rcpf(fmaf(wdr, wdr, wdi*wdi));
                float trm = a01r*a10r - a01i*a10i;
                float tim = a01r*a10i + a01i*a10r;
                float cr = (trm*wdr + tim*wdi) * winv;
                float ci = (tim*wdr - trm*wdi) * winv;
                float kr = a00r - cr, ki = a00i - ci;
                bufA[mA] = make_float2(fmaf(-ki, tA, kr), fmaf(kr, tA, ki));
            }
            // node B
            {
                float wdr = 1.0f + b11r, wdi = b11i;
                float winv = __builtin_amdgcn_rcpf(fmaf(wdr, wdr, wdi*wdi));
                float trm = b01r*b10r - b01i*b10i;
                float tim = b01r*b10i + b01i*b10r;
                float cr = (trm*wdr + tim*wdi) * winv;
                float ci = (tim*wdr - trm*wdi) * winv;
                float kr = b00r - cr, ki = b00i - ci;
                bufA[mB] = make_float2(fmaf(-ki, tB, kr), fmaf(kr, tB, ki));
            }
        }
        // Nyquist m=1024: exact limit k_f = dt * sum_n Re(v00_n)
        if (tid == 0) {
            float s = 0.0f;
            #pragma unroll
            for (int n = 0; n < NPOLE; ++n) s += sA[n].z;
            s_kf_last = make_float2(s, 0.0f);
        }
        __syncthreads();

        // ---- Phase C1: hermitian pack X[0..1024] -> Y[0..1023] in bufB ----
        for (int l = tid; l < NHALF; l += 512) {
            float2 Xm = bufA[l];
            float2 Xn = (l == 0) ? s_kf_last : bufA[NHALF - l];
            if (l == 0) { Xm.y = 0.0f; Xn.y = 0.0f; }   // numpy C2R: DC/Nyquist imag ignored
            float er  = 0.5f*(Xm.x + Xn.x);
            float ei  = 0.5f*(Xm.y - Xn.y);
            float odr = 0.5f*(Xm.x - Xn.x);
            float odi = 0.5f*(Xm.y + Xn.y);
            // e^{+i*pi*l/1024} = cis(2*pi * l/2048)
            const float rev = (float)l * (1.0f / 2048.0f);
            float cs = __builtin_amdgcn_cosf(rev);
            float sn = __builtin_amdgcn_sinf(rev);
            float Or = odr*cs - odi*sn;
            float Oi = odr*sn + odi*cs;
            bufB[l] = make_float2(er - Oi, ei + Or);
        }
        __syncthreads();

        // ---- Phase C2: Stockham radix-2 inverse FFT, N=1024, 10 stages ----
        float2* src = bufB;
        float2* dst = bufA;
        int s = 1;
        for (int t = 0; t < 10; ++t) {
            const int i    = tid;                 // 0..511
            const int lo   = i & (s - 1);
            const int base = i - lo;              // s*p in [0,512)
            float2 twf = stw[base];
            float2 a = src[i];
            float2 b = src[i + 512];
            float2 sum = make_float2(a.x + b.x, a.y + b.y);
            float2 dif = make_float2(a.x - b.x, a.y - b.y);
            float2 tw  = make_float2(dif.x*twf.x - dif.y*twf.y,
                                     dif.x*twf.y + dif.y*twf.x);
            const int o = base*2 + lo;
            dst[o]     = sum;
            dst[o + s] = tw;
            __syncthreads();
            float2* tmp = src; src = dst; dst = tmp;
            s <<= 1;
        }
        // after 10 swaps the result sits in src (== bufB)

        // ---- store: x[2l] = Re(y[l])/N, x[2l+1] = Im(y[l])/N ; float4/thread ----
        const float scale = 1.0f / (float)NHALF;
        float4* outp = (float4*)(g_out + (size_t)h * SLEN);
        {
            const float4 y2 = *((const float4*)&src[2*tid]);
            outp[tid] = make_float4(y2.x*scale, y2.y*scale, y2.z*scale, y2.w*scale);
        }
        // No extra barrier needed before next rep: phase B writes bufA, whose
        // last readers (FFT stage 10) are ordered by that stage's barrier;
        // the store reads bufB, untouched until after the next post-B barrier.
    }
}

extern "C" void kernel_launch(void* const* d_in, const int* in_sizes, int n_in,
                              void* d_out, int out_size, void* d_ws, size_t ws_size,
                              hipStream_t stream) {
    const float* log_dt     = (const float*)d_in[0];
    const float* log_w_real = (const float*)d_in[1];
    const float* w_imag     = (const float*)d_in[2];
    const float* B          = (const float*)d_in[3];
    const float* C          = (const float*)d_in[4];
    const float* P          = (const float*)d_in[5];
    float* out = (float*)d_out;
    const int H = in_sizes[0];   // 512
    s4_nplr_kernel<<<H, 512, 0, stream>>>(log_dt, log_w_real, w_imag, B, C, P, out, 2);
}

// Round 7
// 80.266 us; speedup vs baseline: 1.2351x; 1.2351x over previous
//
#include <hip/hip_runtime.h>
#include <math.h>

#define NPOLE 32     // N2
#define SLEN 2048    // L
#define NHALF 1024   // L/2

// Fused single kernel: one block (512 threads) per head; 2 m-nodes/thread.
// R7: common-denominator Cauchy form. For each pole pair {w, conj(w)}:
//   D = (z-w)(z-w~) = (rho - t2^2) + i*(2ar)*t2,  rho = ar^2+wim^2, z = i*t2
//   numerator(v) = Nr + i*g*t2,  Nr = 2(ar*vr - wim*vi) [node-independent],
//   g = 2*vr.  One rcp per pole*node (was 2), ~54 cyc vs ~72.
// Trig: raw v_sin/v_cos (REVOLUTIONS) on exact dyadic fractions.
// Nyquist m=1024 via exact limit dt*sum(Re v00) = 0.5*sum(g00).
__global__ __launch_bounds__(512) void s4_nplr_kernel(
    const float* __restrict__ g_log_dt,
    const float* __restrict__ g_log_w_real,
    const float* __restrict__ g_w_imag,
    const float* __restrict__ g_B,
    const float* __restrict__ g_C,
    const float* __restrict__ g_P,
    float* __restrict__ g_out)
{
    const int h   = blockIdx.x;
    const int tid = threadIdx.x;

    __shared__ float4 sT0[NPOLE];     // {rho, a2, Nr00, g00}
    __shared__ float4 sT1[NPOLE];     // {Nr01, g01, Nr10, g10}
    __shared__ float2 sT2[NPOLE];     // {Nr11, g11}
    __shared__ __align__(16) float2 bufA[NHALF];
    __shared__ __align__(16) float2 bufB[NHALF];
    __shared__ float2 stw[512];       // FFT twiddles e^{+i*pi*k/512}
    __shared__ float2 s_kf_last;      // k_f[1024]

    const float dt = expf(g_log_dt[h]);

    if (tid < NPOLE) {
        const int n   = tid;
        const int idx = h * NPOLE + n;
        const float ar  = expf(g_log_w_real[idx]) * dt;   // -Re(w)*dt > 0
        const float wim = g_w_imag[idx] * dt;
        const float Br = g_B[2*idx+0], Bi = g_B[2*idx+1];
        const float Cr = g_C[2*idx+0], Ci = g_C[2*idx+1];
        const float Pr = g_P[2*idx+0], Pi = g_P[2*idx+1];
        // v00=dt*B*C, v01=dt*B*conj(P), v10=dt*P*C, v11=dt*|P|^2
        const float v00r = dt*(Br*Cr - Bi*Ci), v00i = dt*(Br*Ci + Bi*Cr);
        const float v01r = dt*(Br*Pr + Bi*Pi), v01i = dt*(Bi*Pr - Br*Pi);
        const float v10r = dt*(Pr*Cr - Pi*Ci), v10i = dt*(Pr*Ci + Pi*Cr);
        const float v11r = dt*(Pr*Pr + Pi*Pi);
        sT0[n] = make_float4(fmaf(ar, ar, wim*wim), ar + ar,
                             2.0f*fmaf(ar, v00r, -wim*v00i), 2.0f*v00r);
        sT1[n] = make_float4(2.0f*fmaf(ar, v01r, -wim*v01i), 2.0f*v01r,
                             2.0f*fmaf(ar, v10r, -wim*v10i), 2.0f*v10r);
        sT2[n] = make_float2(2.0f*ar*v11r, 2.0f*v11r);
    }
    // FFT twiddle table: stw[k] = e^{+i*pi*k/512} = cis(2*pi * k/1024)
    {
        const float rev = (float)tid * (1.0f / 1024.0f);
        stw[tid] = make_float2(__builtin_amdgcn_cosf(rev),
                               __builtin_amdgcn_sinf(rev));
    }
    __syncthreads();

    // ---- Phase B: 2 m-nodes per thread (mA = tid, mB = tid+512) ----
    {
        const int mA = tid;
        const int mB = tid + 512;
        // t = tan(pi*m/2048) = sin(rev)/cos(rev), rev = m/4096 in [0, 0.25)
        const float revA = (float)mA * (1.0f / 4096.0f);
        const float revB = (float)mB * (1.0f / 4096.0f);
        const float tA = __builtin_amdgcn_sinf(revA) *
                         __builtin_amdgcn_rcpf(__builtin_amdgcn_cosf(revA));
        const float tB = __builtin_amdgcn_sinf(revB) *
                         __builtin_amdgcn_rcpf(__builtin_amdgcn_cosf(revB));
        const float t2A = tA + tA, t2B = tB + tB;
        const float t4A = t2A * t2A, t4B = t2B * t2B;

        float a00r=0.f,a00i=0.f,a01r=0.f,a01i=0.f,a10r=0.f,a10i=0.f,a11r=0.f,a11i=0.f;
        float b00r=0.f,b00i=0.f,b01r=0.f,b01i=0.f,b10r=0.f,b10i=0.f,b11r=0.f,b11i=0.f;

        #pragma unroll 8
        for (int n = 0; n < NPOLE; ++n) {
            const float4 T0 = sT0[n];     // broadcast LDS reads
            const float4 T1 = sT1[n];
            const float2 T2 = sT2[n];
            const float rho = T0.x, a2 = T0.y;
            // node A
            {
                float Dr  = rho - t4A;
                float Di  = a2 * t2A;
                float inv = __builtin_amdgcn_rcpf(fmaf(Dr, Dr, Di*Di));
                float Er  = Dr * inv;           // E = conj(D)/|D|^2
                float En  = Di * inv;           // = -Im(E)
                float Fr  = t2A * Er;
                float Fi  = t2A * En;
                // term_r = Nr*Er + g*Fi ; term_i = g*Fr - Nr*En
                a00r = fmaf(T0.z, Er, fmaf(T0.w, Fi, a00r));
                a00i = fmaf(T0.w, Fr, fmaf(-T0.z, En, a00i));
                a01r = fmaf(T1.x, Er, fmaf(T1.y, Fi, a01r));
                a01i = fmaf(T1.y, Fr, fmaf(-T1.x, En, a01i));
                a10r = fmaf(T1.z, Er, fmaf(T1.w, Fi, a10r));
                a10i = fmaf(T1.w, Fr, fmaf(-T1.z, En, a10i));
                a11r = fmaf(T2.x, Er, fmaf(T2.y, Fi, a11r));
                a11i = fmaf(T2.y, Fr, fmaf(-T2.x, En, a11i));
            }
            // node B
            {
                float Dr  = rho - t4B;
                float Di  = a2 * t2B;
                float inv = __builtin_amdgcn_rcpf(fmaf(Dr, Dr, Di*Di));
                float Er  = Dr * inv;
                float En  = Di * inv;
                float Fr  = t2B * Er;
                float Fi  = t2B * En;
                b00r = fmaf(T0.z, Er, fmaf(T0.w, Fi, b00r));
                b00i = fmaf(T0.w, Fr, fmaf(-T0.z, En, b00i));
                b01r = fmaf(T1.x, Er, fmaf(T1.y, Fi, b01r));
                b01i = fmaf(T1.y, Fr, fmaf(-T1.x, En, b01i));
                b10r = fmaf(T1.z, Er, fmaf(T1.w, Fi, b10r));
                b10i = fmaf(T1.w, Fr, fmaf(-T1.z, En, b10i));
                b11r = fmaf(T2.x, Er, fmaf(T2.y, Fi, b11r));
                b11i = fmaf(T2.y, Fr, fmaf(-T2.x, En, b11i));
            }
        }

        // Woodbury + spectral factor (1 + i*t), node A
        {
            float wdr = 1.0f + a11r, wdi = a11i;
            float winv = __builtin_amdgcn_rcpf(fmaf(wdr, wdr, wdi*wdi));
            float trm = a01r*a10r - a01i*a10i;
            float tim = a01r*a10i + a01i*a10r;
            float cr = (trm*wdr + tim*wdi) * winv;
            float ci = (tim*wdr - trm*wdi) * winv;
            float kr = a00r - cr, ki = a00i - ci;
            bufA[mA] = make_float2(fmaf(-ki, tA, kr), fmaf(kr, tA, ki));
        }
        // node B
        {
            float wdr = 1.0f + b11r, wdi = b11i;
            float winv = __builtin_amdgcn_rcpf(fmaf(wdr, wdr, wdi*wdi));
            float trm = b01r*b10r - b01i*b10i;
            float tim = b01r*b10i + b01i*b10r;
            float cr = (trm*wdr + tim*wdi) * winv;
            float ci = (tim*wdr - trm*wdi) * winv;
            float kr = b00r - cr, ki = b00i - ci;
            bufA[mB] = make_float2(fmaf(-ki, tB, kr), fmaf(kr, tB, ki));
        }
    }
    // Nyquist m=1024: exact limit k_f = dt * sum_n Re(v00_n) = 0.5 * sum g00
    if (tid == 0) {
        float s = 0.0f;
        #pragma unroll
        for (int n = 0; n < NPOLE; ++n) s += sT0[n].w;
        s_kf_last = make_float2(0.5f * s, 0.0f);
    }
    __syncthreads();

    // ---- Phase C1: hermitian pack X[0..1024] -> Y[0..1023] in bufB ----
    for (int l = tid; l < NHALF; l += 512) {
        float2 Xm = bufA[l];
        float2 Xn = (l == 0) ? s_kf_last : bufA[NHALF - l];
        if (l == 0) { Xm.y = 0.0f; Xn.y = 0.0f; }   // numpy C2R: DC/Nyquist imag ignored
        float er  = 0.5f*(Xm.x + Xn.x);
        float ei  = 0.5f*(Xm.y - Xn.y);
        float odr = 0.5f*(Xm.x - Xn.x);
        float odi = 0.5f*(Xm.y + Xn.y);
        // e^{+i*pi*l/1024} = cis(2*pi * l/2048)
        const float rev = (float)l * (1.0f / 2048.0f);
        float cs = __builtin_amdgcn_cosf(rev);
        float sn = __builtin_amdgcn_sinf(rev);
        float Or = odr*cs - odi*sn;
        float Oi = odr*sn + odi*cs;
        bufB[l] = make_float2(er - Oi, ei + Or);
    }
    __syncthreads();

    // ---- Phase C2: Stockham radix-2 inverse FFT, N=1024, 10 stages ----
    float2* src = bufB;
    float2* dst = bufA;
    int s = 1;
    for (int t = 0; t < 10; ++t) {
        const int i    = tid;                 // 0..511
        const int lo   = i & (s - 1);
        const int base = i - lo;              // s*p in [0,512)
        float2 twf = stw[base];
        float2 a = src[i];
        float2 b = src[i + 512];
        float2 sum = make_float2(a.x + b.x, a.y + b.y);
        float2 dif = make_float2(a.x - b.x, a.y - b.y);
        float2 tw  = make_float2(dif.x*twf.x - dif.y*twf.y,
                                 dif.x*twf.y + dif.y*twf.x);
        const int o = base*2 + lo;
        dst[o]     = sum;
        dst[o + s] = tw;
        __syncthreads();
        float2* tmp = src; src = dst; dst = tmp;
        s <<= 1;
    }
    // after 10 swaps the result sits in src (== bufB)

    // ---- store: x[2l] = Re(y[l])/N, x[2l+1] = Im(y[l])/N ; float4/thread ----
    const float scale = 1.0f / (float)NHALF;
    float4* outp = (float4*)(g_out + (size_t)h * SLEN);
    {
        const float4 y2 = *((const float4*)&src[2*tid]);
        outp[tid] = make_float4(y2.x*scale, y2.y*scale, y2.z*scale, y2.w*scale);
    }
}

extern "C" void kernel_launch(void* const* d_in, const int* in_sizes, int n_in,
                              void* d_out, int out_size, void* d_ws, size_t ws_size,
                              hipStream_t stream) {
    const float* log_dt     = (const float*)d_in[0];
    const float* log_w_real = (const float*)d_in[1];
    const float* w_imag     = (const float*)d_in[2];
    const float* B          = (const float*)d_in[3];
    const float* C          = (const float*)d_in[4];
    const float* P          = (const float*)d_in[5];
    float* out = (float*)d_out;
    const int H = in_sizes[0];   // 512
    s4_nplr_kernel<<<H, 512, 0, stream>>>(log_dt, log_w_real, w_imag, B, C, P, out);
}

// Round 8
// 79.134 us; speedup vs baseline: 1.2528x; 1.0143x over previous
//
#include <hip/hip_runtime.h>
#include <math.h>

#define NPOLE 32     // N2
#define SLEN 2048    // L
#define NHALF 1024   // L/2

// Fused single kernel: one block (512 threads) per head; 2 m-nodes/thread.
// Phase B (R7, validated): common-denominator Cauchy form, 1 rcp/pole*node.
// Phase C2 (R8): radix-4 Stockham IFFT (5 stages), derived by exact
// composition of two verified radix-2 stages -- halves LDS traffic+barriers.
// Trig: raw v_sin/v_cos (REVOLUTIONS) on exact dyadic fractions.
__global__ __launch_bounds__(512) void s4_nplr_kernel(
    const float* __restrict__ g_log_dt,
    const float* __restrict__ g_log_w_real,
    const float* __restrict__ g_w_imag,
    const float* __restrict__ g_B,
    const float* __restrict__ g_C,
    const float* __restrict__ g_P,
    float* __restrict__ g_out)
{
    const int h   = blockIdx.x;
    const int tid = threadIdx.x;

    __shared__ float4 sT0[NPOLE];     // {rho, a2, Nr00, g00}
    __shared__ float4 sT1[NPOLE];     // {Nr01, g01, Nr10, g10}
    __shared__ float2 sT2[NPOLE];     // {Nr11, g11}
    __shared__ __align__(16) float2 bufA[NHALF];
    __shared__ __align__(16) float2 bufB[NHALF];
    __shared__ float2 stw[512];       // twiddles cis(2*pi*k/1024)
    __shared__ float2 s_kf_last;      // k_f[1024]

    const float dt = expf(g_log_dt[h]);

    if (tid < NPOLE) {
        const int n   = tid;
        const int idx = h * NPOLE + n;
        const float ar  = expf(g_log_w_real[idx]) * dt;   // -Re(w)*dt > 0
        const float wim = g_w_imag[idx] * dt;
        const float Br = g_B[2*idx+0], Bi = g_B[2*idx+1];
        const float Cr = g_C[2*idx+0], Ci = g_C[2*idx+1];
        const float Pr = g_P[2*idx+0], Pi = g_P[2*idx+1];
        // v00=dt*B*C, v01=dt*B*conj(P), v10=dt*P*C, v11=dt*|P|^2
        const float v00r = dt*(Br*Cr - Bi*Ci), v00i = dt*(Br*Ci + Bi*Cr);
        const float v01r = dt*(Br*Pr + Bi*Pi), v01i = dt*(Bi*Pr - Br*Pi);
        const float v10r = dt*(Pr*Cr - Pi*Ci), v10i = dt*(Pr*Ci + Pi*Cr);
        const float v11r = dt*(Pr*Pr + Pi*Pi);
        sT0[n] = make_float4(fmaf(ar, ar, wim*wim), ar + ar,
                             2.0f*fmaf(ar, v00r, -wim*v00i), 2.0f*v00r);
        sT1[n] = make_float4(2.0f*fmaf(ar, v01r, -wim*v01i), 2.0f*v01r,
                             2.0f*fmaf(ar, v10r, -wim*v10i), 2.0f*v10r);
        sT2[n] = make_float2(2.0f*ar*v11r, 2.0f*v11r);
    }
    // twiddle table: stw[k] = cis(2*pi * k/1024)
    {
        const float rev = (float)tid * (1.0f / 1024.0f);
        stw[tid] = make_float2(__builtin_amdgcn_cosf(rev),
                               __builtin_amdgcn_sinf(rev));
    }
    __syncthreads();

    // ---- Phase B: 2 m-nodes per thread (mA = tid, mB = tid+512) ----
    {
        const int mA = tid;
        const int mB = tid + 512;
        const float revA = (float)mA * (1.0f / 4096.0f);
        const float revB = (float)mB * (1.0f / 4096.0f);
        const float tA = __builtin_amdgcn_sinf(revA) *
                         __builtin_amdgcn_rcpf(__builtin_amdgcn_cosf(revA));
        const float tB = __builtin_amdgcn_sinf(revB) *
                         __builtin_amdgcn_rcpf(__builtin_amdgcn_cosf(revB));
        const float t2A = tA + tA, t2B = tB + tB;
        const float t4A = t2A * t2A, t4B = t2B * t2B;

        float a00r=0.f,a00i=0.f,a01r=0.f,a01i=0.f,a10r=0.f,a10i=0.f,a11r=0.f,a11i=0.f;
        float b00r=0.f,b00i=0.f,b01r=0.f,b01i=0.f,b10r=0.f,b10i=0.f,b11r=0.f,b11i=0.f;

        #pragma unroll 8
        for (int n = 0; n < NPOLE; ++n) {
            const float4 T0 = sT0[n];
            const float4 T1 = sT1[n];
            const float2 T2 = sT2[n];
            const float rho = T0.x, a2 = T0.y;
            // node A
            {
                float Dr  = rho - t4A;
                float Di  = a2 * t2A;
                float inv = __builtin_amdgcn_rcpf(fmaf(Dr, Dr, Di*Di));
                float Er  = Dr * inv;
                float En  = Di * inv;
                float Fr  = t2A * Er;
                float Fi  = t2A * En;
                a00r = fmaf(T0.z, Er, fmaf(T0.w, Fi, a00r));
                a00i = fmaf(T0.w, Fr, fmaf(-T0.z, En, a00i));
                a01r = fmaf(T1.x, Er, fmaf(T1.y, Fi, a01r));
                a01i = fmaf(T1.y, Fr, fmaf(-T1.x, En, a01i));
                a10r = fmaf(T1.z, Er, fmaf(T1.w, Fi, a10r));
                a10i = fmaf(T1.w, Fr, fmaf(-T1.z, En, a10i));
                a11r = fmaf(T2.x, Er, fmaf(T2.y, Fi, a11r));
                a11i = fmaf(T2.y, Fr, fmaf(-T2.x, En, a11i));
            }
            // node B
            {
                float Dr  = rho - t4B;
                float Di  = a2 * t2B;
                float inv = __builtin_amdgcn_rcpf(fmaf(Dr, Dr, Di*Di));
                float Er  = Dr * inv;
                float En  = Di * inv;
                float Fr  = t2B * Er;
                float Fi  = t2B * En;
                b00r = fmaf(T0.z, Er, fmaf(T0.w, Fi, b00r));
                b00i = fmaf(T0.w, Fr, fmaf(-T0.z, En, b00i));
                b01r = fmaf(T1.x, Er, fmaf(T1.y, Fi, b01r));
                b01i = fmaf(T1.y, Fr, fmaf(-T1.x, En, b01i));
                b10r = fmaf(T1.z, Er, fmaf(T1.w, Fi, b10r));
                b10i = fmaf(T1.w, Fr, fmaf(-T1.z, En, b10i));
                b11r = fmaf(T2.x, Er, fmaf(T2.y, Fi, b11r));
                b11i = fmaf(T2.y, Fr, fmaf(-T2.x, En, b11i));
            }
        }

        // Woodbury + spectral factor (1 + i*t), node A
        {
            float wdr = 1.0f + a11r, wdi = a11i;
            float winv = __builtin_amdgcn_rcpf(fmaf(wdr, wdr, wdi*wdi));
            float trm = a01r*a10r - a01i*a10i;
            float tim = a01r*a10i + a01i*a10r;
            float cr = (trm*wdr + tim*wdi) * winv;
            float ci = (tim*wdr - trm*wdi) * winv;
            float kr = a00r - cr, ki = a00i - ci;
            bufA[mA] = make_float2(fmaf(-ki, tA, kr), fmaf(kr, tA, ki));
        }
        // node B
        {
            float wdr = 1.0f + b11r, wdi = b11i;
            float winv = __builtin_amdgcn_rcpf(fmaf(wdr, wdr, wdi*wdi));
            float trm = b01r*b10r - b01i*b10i;
            float tim = b01r*b10i + b01i*b10r;
            float cr = (trm*wdr + tim*wdi) * winv;
            float ci = (tim*wdr - trm*wdi) * winv;
            float kr = b00r - cr, ki = b00i - ci;
            bufA[mB] = make_float2(fmaf(-ki, tB, kr), fmaf(kr, tB, ki));
        }
    }
    // Nyquist m=1024: exact limit k_f = dt * sum_n Re(v00_n) = 0.5 * sum g00
    if (tid == 0) {
        float s = 0.0f;
        #pragma unroll
        for (int n = 0; n < NPOLE; ++n) s += sT0[n].w;
        s_kf_last = make_float2(0.5f * s, 0.0f);
    }
    __syncthreads();

    // ---- Phase C1: hermitian pack X[0..1024] -> Y[0..1023] in bufB ----
    for (int l = tid; l < NHALF; l += 512) {
        float2 Xm = bufA[l];
        float2 Xn = (l == 0) ? s_kf_last : bufA[NHALF - l];
        if (l == 0) { Xm.y = 0.0f; Xn.y = 0.0f; }   // numpy C2R: DC/Nyquist imag ignored
        float er  = 0.5f*(Xm.x + Xn.x);
        float ei  = 0.5f*(Xm.y - Xn.y);
        float odr = 0.5f*(Xm.x - Xn.x);
        float odi = 0.5f*(Xm.y + Xn.y);
        const float rev = (float)l * (1.0f / 2048.0f);
        float cs = __builtin_amdgcn_cosf(rev);
        float sn = __builtin_amdgcn_sinf(rev);
        float Or = odr*cs - odi*sn;
        float Oi = odr*sn + odi*cs;
        bufB[l] = make_float2(er - Oi, ei + Or);
    }
    __syncthreads();

    // ---- Phase C2: Stockham radix-4 inverse FFT, N=1024, 5 stages ----
    // Exact composition of two verified radix-2 stages (s, then 2s):
    //   x_k = src[j + 256k], q = j mod s, sp = j - q, w = stw[sp]
    //   v0 = (x0+x2)+(x1+x3)              -> dst[4sp+q]
    //   v1 = w * ((x0-x2)+i(x1-x3))       -> dst[4sp+q+s]
    //   v2 = w^2*((x0+x2)-(x1+x3))        -> dst[4sp+q+2s]
    //   v3 = w^3*((x0-x2)-i(x1-x3))       -> dst[4sp+q+3s]
    // (the i comes from cis(theta + 1/4 rev) = i*cis(theta))
    float2* src = bufB;
    float2* dst = bufA;
    int s = 1;
    #pragma unroll
    for (int t = 0; t < 5; ++t) {
        if (tid < 256) {
            const int j  = tid;
            const int q  = j & (s - 1);
            const int sp = j - q;            // multiple of s, < 256
            float2 x0 = src[j];
            float2 x1 = src[j + 256];
            float2 x2 = src[j + 512];
            float2 x3 = src[j + 768];
            float e0r = x0.x + x2.x, e0i = x0.y + x2.y;   // x0+x2
            float d0r = x0.x - x2.x, d0i = x0.y - x2.y;   // x0-x2
            float e1r = x1.x + x3.x, e1i = x1.y + x3.y;   // x1+x3
            float d1r = x1.x - x3.x, d1i = x1.y - x3.y;   // x1-x3
            float pr = d0r - d1i, pi = d0i + d1r;         // (x0-x2)+i(x1-x3)
            float qr = d0r + d1i, qi = d0i - d1r;         // (x0-x2)-i(x1-x3)
            float r0r = e0r + e1r, r0i = e0i + e1i;
            float r2r = e0r - e1r, r2i = e0i - e1i;
            float2 w1 = stw[sp];
            float2 w2 = stw[2*sp];
            float2 w3 = make_float2(w1.x*w2.x - w1.y*w2.y,
                                    w1.x*w2.y + w1.y*w2.x);
            const int o = 4*sp + q;
            dst[o]       = make_float2(r0r, r0i);
            dst[o + s]   = make_float2(pr*w1.x - pi*w1.y, pr*w1.y + pi*w1.x);
            dst[o + 2*s] = make_float2(r2r*w2.x - r2i*w2.y, r2r*w2.y + r2i*w2.x);
            dst[o + 3*s] = make_float2(qr*w3.x - qi*w3.y, qr*w3.y + qi*w3.x);
        }
        __syncthreads();
        float2* tmp = src; src = dst; dst = tmp;
        s <<= 2;
    }
    // 5 swaps (odd) -> result in src == bufA

    // ---- store: x[2l] = Re(y[l])/N, x[2l+1] = Im(y[l])/N ; float4/thread ----
    const float scale = 1.0f / (float)NHALF;
    float4* outp = (float4*)(g_out + (size_t)h * SLEN);
    {
        const float4 y2 = *((const float4*)&src[2*tid]);
        outp[tid] = make_float4(y2.x*scale, y2.y*scale, y2.z*scale, y2.w*scale);
    }
}

extern "C" void kernel_launch(void* const* d_in, const int* in_sizes, int n_in,
                              void* d_out, int out_size, void* d_ws, size_t ws_size,
                              hipStream_t stream) {
    const float* log_dt     = (const float*)d_in[0];
    const float* log_w_real = (const float*)d_in[1];
    const float* w_imag     = (const float*)d_in[2];
    const float* B          = (const float*)d_in[3];
    const float* C          = (const float*)d_in[4];
    const float* P          = (const float*)d_in[5];
    float* out = (float*)d_out;
    const int H = in_sizes[0];   // 512
    s4_nplr_kernel<<<H, 512, 0, stream>>>(log_dt, log_w_real, w_imag, B, C, P, out);
}

// Round 9
// 77.675 us; speedup vs baseline: 1.2763x; 1.0188x over previous
//
#include <hip/hip_runtime.h>
#include <math.h>

#define NPOLE 32     // N2
#define SLEN 2048    // L
#define NHALF 1024   // L/2

// Fused single kernel: one block (512 threads) per head; 2 m-nodes/thread.
// Phase B (R7, validated): common-denominator Cauchy form, 1 rcp/pole*node.
// Phase C (R9): hermitian pack fused into the first radix-4 Stockham stage
// (saves one 8KB LDS round-trip + 1 barrier); 1/N IFFT scale folded into the
// pack's 0.5 prefactor (FFT linearity) so the store is a pure LDS->global copy.
// Trig: raw v_sin/v_cos (REVOLUTIONS) on exact dyadic fractions.
__global__ __launch_bounds__(512) void s4_nplr_kernel(
    const float* __restrict__ g_log_dt,
    const float* __restrict__ g_log_w_real,
    const float* __restrict__ g_w_imag,
    const float* __restrict__ g_B,
    const float* __restrict__ g_C,
    const float* __restrict__ g_P,
    float* __restrict__ g_out)
{
    const int h   = blockIdx.x;
    const int tid = threadIdx.x;

    __shared__ float4 sT0[NPOLE];     // {rho, a2, Nr00, g00}
    __shared__ float4 sT1[NPOLE];     // {Nr01, g01, Nr10, g10}
    __shared__ float2 sT2[NPOLE];     // {Nr11, g11}
    __shared__ __align__(16) float2 bufA[NHALF];
    __shared__ __align__(16) float2 bufB[NHALF];
    __shared__ float2 stw[512];       // twiddles cis(2*pi*k/1024)
    __shared__ float2 s_kf_last;      // k_f[1024]

    const float dt = expf(g_log_dt[h]);

    if (tid < NPOLE) {
        const int n   = tid;
        const int idx = h * NPOLE + n;
        const float ar  = expf(g_log_w_real[idx]) * dt;   // -Re(w)*dt > 0
        const float wim = g_w_imag[idx] * dt;
        const float Br = g_B[2*idx+0], Bi = g_B[2*idx+1];
        const float Cr = g_C[2*idx+0], Ci = g_C[2*idx+1];
        const float Pr = g_P[2*idx+0], Pi = g_P[2*idx+1];
        // v00=dt*B*C, v01=dt*B*conj(P), v10=dt*P*C, v11=dt*|P|^2
        const float v00r = dt*(Br*Cr - Bi*Ci), v00i = dt*(Br*Ci + Bi*Cr);
        const float v01r = dt*(Br*Pr + Bi*Pi), v01i = dt*(Bi*Pr - Br*Pi);
        const float v10r = dt*(Pr*Cr - Pi*Ci), v10i = dt*(Pr*Ci + Pi*Cr);
        const float v11r = dt*(Pr*Pr + Pi*Pi);
        sT0[n] = make_float4(fmaf(ar, ar, wim*wim), ar + ar,
                             2.0f*fmaf(ar, v00r, -wim*v00i), 2.0f*v00r);
        sT1[n] = make_float4(2.0f*fmaf(ar, v01r, -wim*v01i), 2.0f*v01r,
                             2.0f*fmaf(ar, v10r, -wim*v10i), 2.0f*v10r);
        sT2[n] = make_float2(2.0f*ar*v11r, 2.0f*v11r);
    }
    // twiddle table: stw[k] = cis(2*pi * k/1024)
    {
        const float rev = (float)tid * (1.0f / 1024.0f);
        stw[tid] = make_float2(__builtin_amdgcn_cosf(rev),
                               __builtin_amdgcn_sinf(rev));
    }
    __syncthreads();

    // ---- Phase B: 2 m-nodes per thread (mA = tid, mB = tid+512) ----
    {
        const int mA = tid;
        const int mB = tid + 512;
        const float revA = (float)mA * (1.0f / 4096.0f);
        const float revB = (float)mB * (1.0f / 4096.0f);
        const float tA = __builtin_amdgcn_sinf(revA) *
                         __builtin_amdgcn_rcpf(__builtin_amdgcn_cosf(revA));
        const float tB = __builtin_amdgcn_sinf(revB) *
                         __builtin_amdgcn_rcpf(__builtin_amdgcn_cosf(revB));
        const float t2A = tA + tA, t2B = tB + tB;
        const float t4A = t2A * t2A, t4B = t2B * t2B;

        float a00r=0.f,a00i=0.f,a01r=0.f,a01i=0.f,a10r=0.f,a10i=0.f,a11r=0.f,a11i=0.f;
        float b00r=0.f,b00i=0.f,b01r=0.f,b01i=0.f,b10r=0.f,b10i=0.f,b11r=0.f,b11i=0.f;

        #pragma unroll 8
        for (int n = 0; n < NPOLE; ++n) {
            const float4 T0 = sT0[n];
            const float4 T1 = sT1[n];
            const float2 T2 = sT2[n];
            const float rho = T0.x, a2 = T0.y;
            // node A
            {
                float Dr  = rho - t4A;
                float Di  = a2 * t2A;
                float inv = __builtin_amdgcn_rcpf(fmaf(Dr, Dr, Di*Di));
                float Er  = Dr * inv;
                float En  = Di * inv;
                float Fr  = t2A * Er;
                float Fi  = t2A * En;
                a00r = fmaf(T0.z, Er, fmaf(T0.w, Fi, a00r));
                a00i = fmaf(T0.w, Fr, fmaf(-T0.z, En, a00i));
                a01r = fmaf(T1.x, Er, fmaf(T1.y, Fi, a01r));
                a01i = fmaf(T1.y, Fr, fmaf(-T1.x, En, a01i));
                a10r = fmaf(T1.z, Er, fmaf(T1.w, Fi, a10r));
                a10i = fmaf(T1.w, Fr, fmaf(-T1.z, En, a10i));
                a11r = fmaf(T2.x, Er, fmaf(T2.y, Fi, a11r));
                a11i = fmaf(T2.y, Fr, fmaf(-T2.x, En, a11i));
            }
            // node B
            {
                float Dr  = rho - t4B;
                float Di  = a2 * t2B;
                float inv = __builtin_amdgcn_rcpf(fmaf(Dr, Dr, Di*Di));
                float Er  = Dr * inv;
                float En  = Di * inv;
                float Fr  = t2B * Er;
                float Fi  = t2B * En;
                b00r = fmaf(T0.z, Er, fmaf(T0.w, Fi, b00r));
                b00i = fmaf(T0.w, Fr, fmaf(-T0.z, En, b00i));
                b01r = fmaf(T1.x, Er, fmaf(T1.y, Fi, b01r));
                b01i = fmaf(T1.y, Fr, fmaf(-T1.x, En, b01i));
                b10r = fmaf(T1.z, Er, fmaf(T1.w, Fi, b10r));
                b10i = fmaf(T1.w, Fr, fmaf(-T1.z, En, b10i));
                b11r = fmaf(T2.x, Er, fmaf(T2.y, Fi, b11r));
                b11i = fmaf(T2.y, Fr, fmaf(-T2.x, En, b11i));
            }
        }

        // Woodbury + spectral factor (1 + i*t), node A
        {
            float wdr = 1.0f + a11r, wdi = a11i;
            float winv = __builtin_amdgcn_rcpf(fmaf(wdr, wdr, wdi*wdi));
            float trm = a01r*a10r - a01i*a10i;
            float tim = a01r*a10i + a01i*a10r;
            float cr = (trm*wdr + tim*wdi) * winv;
            float ci = (tim*wdr - trm*wdi) * winv;
            float kr = a00r - cr, ki = a00i - ci;
            bufA[mA] = make_float2(fmaf(-ki, tA, kr), fmaf(kr, tA, ki));
        }
        // node B
        {
            float wdr = 1.0f + b11r, wdi = b11i;
            float winv = __builtin_amdgcn_rcpf(fmaf(wdr, wdr, wdi*wdi));
            float trm = b01r*b10r - b01i*b10i;
            float tim = b01r*b10i + b01i*b10r;
            float cr = (trm*wdr + tim*wdi) * winv;
            float ci = (tim*wdr - trm*wdi) * winv;
            float kr = b00r - cr, ki = b00i - ci;
            bufA[mB] = make_float2(fmaf(-ki, tB, kr), fmaf(kr, tB, ki));
        }
    }
    // Nyquist m=1024: exact limit k_f = dt * sum_n Re(v00_n) = 0.5 * sum g00
    if (tid == 0) {
        float s = 0.0f;
        #pragma unroll
        for (int n = 0; n < NPOLE; ++n) s += sT0[n].w;
        s_kf_last = make_float2(0.5f * s, 0.0f);
    }
    __syncthreads();

    // ---- Phase C: fused hermitian pack + radix-4 stage 1 (s=1) ----
    // Y[l] = E + i*O (O twiddled by cis(l/2048 rev)); SCALE = 0.5/1024 folds
    // the IFFT 1/N into the pack (FFT linearity) so the store is a raw copy.
    const float SCALE = 0.5f / 1024.0f;
    if (tid < 256) {
        const int j = tid;
        float2 Y[4];
        #pragma unroll
        for (int k = 0; k < 4; ++k) {
            const int l = j + (k << 8);
            float2 Xm = bufA[l];
            float2 Xn;
            if (l == 0) { Xn = s_kf_last; Xm.y = 0.0f; Xn.y = 0.0f; }
            else          Xn = bufA[NHALF - l];
            float er  = SCALE*(Xm.x + Xn.x);
            float ei  = SCALE*(Xm.y - Xn.y);
            float odr = SCALE*(Xm.x - Xn.x);
            float odi = SCALE*(Xm.y + Xn.y);
            const float rev = (float)l * (1.0f / 2048.0f);
            float cs = __builtin_amdgcn_cosf(rev);
            float sn = __builtin_amdgcn_sinf(rev);
            float Or = odr*cs - odi*sn;
            float Oi = odr*sn + odi*cs;
            Y[k] = make_float2(er - Oi, ei + Or);
        }
        // radix-4 butterfly, s=1: q=0, sp=j, outputs at 4j+{0,1,2,3}
        float e0r = Y[0].x + Y[2].x, e0i = Y[0].y + Y[2].y;
        float d0r = Y[0].x - Y[2].x, d0i = Y[0].y - Y[2].y;
        float e1r = Y[1].x + Y[3].x, e1i = Y[1].y + Y[3].y;
        float d1r = Y[1].x - Y[3].x, d1i = Y[1].y - Y[3].y;
        float pr = d0r - d1i, pi = d0i + d1r;
        float qr = d0r + d1i, qi = d0i - d1r;
        float r0r = e0r + e1r, r0i = e0i + e1i;
        float r2r = e0r - e1r, r2i = e0i - e1i;
        float2 w1 = stw[j];
        float2 w2 = stw[2*j];
        float2 w3 = make_float2(w1.x*w2.x - w1.y*w2.y,
                                w1.x*w2.y + w1.y*w2.x);
        const int o = 4*j;
        bufB[o]     = make_float2(r0r, r0i);
        bufB[o + 1] = make_float2(pr*w1.x - pi*w1.y, pr*w1.y + pi*w1.x);
        bufB[o + 2] = make_float2(r2r*w2.x - r2i*w2.y, r2r*w2.y + r2i*w2.x);
        bufB[o + 3] = make_float2(qr*w3.x - qi*w3.y, qr*w3.y + qi*w3.x);
    }
    __syncthreads();

    // ---- remaining radix-4 stages: s = 4, 16, 64, 256 ----
    float2* src = bufB;
    float2* dst = bufA;
    int s = 4;
    #pragma unroll
    for (int t = 0; t < 4; ++t) {
        if (tid < 256) {
            const int j  = tid;
            const int q  = j & (s - 1);
            const int sp = j - q;            // multiple of s, < 256
            float2 x0 = src[j];
            float2 x1 = src[j + 256];
            float2 x2 = src[j + 512];
            float2 x3 = src[j + 768];
            float e0r = x0.x + x2.x, e0i = x0.y + x2.y;
            float d0r = x0.x - x2.x, d0i = x0.y - x2.y;
            float e1r = x1.x + x3.x, e1i = x1.y + x3.y;
            float d1r = x1.x - x3.x, d1i = x1.y - x3.y;
            float pr = d0r - d1i, pi = d0i + d1r;
            float qr = d0r + d1i, qi = d0i - d1r;
            float r0r = e0r + e1r, r0i = e0i + e1i;
            float r2r = e0r - e1r, r2i = e0i - e1i;
            float2 w1 = stw[sp];
            float2 w2 = stw[2*sp];
            float2 w3 = make_float2(w1.x*w2.x - w1.y*w2.y,
                                    w1.x*w2.y + w1.y*w2.x);
            const int o = 4*sp + q;
            dst[o]       = make_float2(r0r, r0i);
            dst[o + s]   = make_float2(pr*w1.x - pi*w1.y, pr*w1.y + pi*w1.x);
            dst[o + 2*s] = make_float2(r2r*w2.x - r2i*w2.y, r2r*w2.y + r2i*w2.x);
            dst[o + 3*s] = make_float2(qr*w3.x - qi*w3.y, qr*w3.y + qi*w3.x);
        }
        __syncthreads();
        float2* tmp = src; src = dst; dst = tmp;
        s <<= 2;
    }
    // trace: bufB->A (swap: src=A), A->B (src=B), B->A (src=A), A->B (src=B)
    // result in src == bufB

    // ---- store: pure copy (scale already folded into the pack) ----
    float4* outp = (float4*)(g_out + (size_t)h * SLEN);
    outp[tid] = *((const float4*)&src[2*tid]);
}

extern "C" void kernel_launch(void* const* d_in, const int* in_sizes, int n_in,
                              void* d_out, int out_size, void* d_ws, size_t ws_size,
                              hipStream_t stream) {
    const float* log_dt     = (const float*)d_in[0];
    const float* log_w_real = (const float*)d_in[1];
    const float* w_imag     = (const float*)d_in[2];
    const float* B          = (const float*)d_in[3];
    const float* C          = (const float*)d_in[4];
    const float* P          = (const float*)d_in[5];
    float* out = (float*)d_out;
    const int H = in_sizes[0];   // 512
    s4_nplr_kernel<<<H, 512, 0, stream>>>(log_dt, log_w_real, w_imag, B, C, P, out);
}